// Round 7
// baseline (14631.772 us; speedup 1.0000x reference)
//
#include <hip/hip_runtime.h>
#include <math.h>

#define BATCH 32
#define SEQ   512
#define IDIM  256
#define RDIM  2048
#define ODIM  256
#define LEAK  0.3f

#define SCAN_BLOCKS  256
#define SCAN_THREADS 512
#define ROWS_PER_BLK 8   // RDIM / SCAN_BLOCKS
#define NGROUP       8   // k-groups of 256 rows (32 blocks each)

typedef float f4 __attribute__((ext_vector_type(4)));

__device__ __forceinline__ unsigned ld_flag(const unsigned* p) {
    return __hip_atomic_load(p, __ATOMIC_RELAXED, __HIP_MEMORY_SCOPE_AGENT);
}

// whole-wave poll of the 8 group counters (one sc1 load instruction, 8 lines)
// returns 8-bit readiness mask; wave-uniform.
__device__ __forceinline__ unsigned poll_ready(const unsigned* flags, int lane,
                                               unsigned target) {
    unsigned c = ld_flag(&flags[(lane & 7) * 16]);
    unsigned long long bal = __ballot(c >= target);
    return (unsigned)bal & 0xFFu;
}

// ---------------------------------------------------------------------------
// init: copy initial state into states slot 0, zero flags region
// ---------------------------------------------------------------------------
__global__ void esn_init(const float* __restrict__ s0, float* __restrict__ states,
                         unsigned* __restrict__ flags) {
    int idx = blockIdx.x * blockDim.x + threadIdx.x;
    const int n4 = (BATCH * RDIM) / 4;
    if (idx < n4) {
        ((float4*)states)[idx] = ((const float4*)s0)[idx];
    }
    if (idx < 512) flags[idx] = 0u;
}

// ---------------------------------------------------------------------------
// u_proj GEMM: up[m][r] = sum_i u[b][t][i] * Win[r][i] + bias[r],  m = t*32+b
// Written into states slots 1..512 (up[t] aliases states[t+1]; consumed by the
// finalize lane via sc1 read before the same lane overwrites it).
// ---------------------------------------------------------------------------
#define UP_THREADS 256
__global__ __launch_bounds__(UP_THREADS) void esn_uproj(
    const float* __restrict__ u,      // (B, T, I)
    const float* __restrict__ Win,    // (R, I)
    const float* __restrict__ bias,   // (R)
    float* __restrict__ up)           // (T*B, R) == states + B*R
{
    __shared__ float St[32][68];
    __shared__ float Wt[32][68];

    const int tid  = threadIdx.x;
    const int row0 = blockIdx.x * 64;   // m-tile (m = t*32+b)
    const int o0   = blockIdx.y * 64;   // r-tile

    const int lr = tid >> 3;
    const int lk = (tid & 7) * 4;
    const int tx = tid & 15;
    const int ty = tid >> 4;

    const int m0 = row0 + lr;
    const int m1 = row0 + 32 + lr;
    const float* u0 = u + ((size_t)(m0 & 31) * SEQ + (m0 >> 5)) * IDIM;
    const float* u1 = u + ((size_t)(m1 & 31) * SEQ + (m1 >> 5)) * IDIM;

    float acc[4][4] = {};

    for (int kt = 0; kt < IDIM; kt += 32) {
        float4 a0 = *(const float4*)(u0 + kt + lk);
        float4 a1 = *(const float4*)(u1 + kt + lk);
        float4 w0 = *(const float4*)(Win + (size_t)(o0 + lr)      * IDIM + kt + lk);
        float4 w1 = *(const float4*)(Win + (size_t)(o0 + 32 + lr) * IDIM + kt + lk);
        __syncthreads();
        float av0[4] = {a0.x, a0.y, a0.z, a0.w};
        float av1[4] = {a1.x, a1.y, a1.z, a1.w};
        float wv0[4] = {w0.x, w0.y, w0.z, w0.w};
        float wv1[4] = {w1.x, w1.y, w1.z, w1.w};
        #pragma unroll
        for (int j = 0; j < 4; ++j) {
            St[lk + j][lr]      = av0[j];
            St[lk + j][32 + lr] = av1[j];
            Wt[lk + j][lr]      = wv0[j];
            Wt[lk + j][32 + lr] = wv1[j];
        }
        __syncthreads();
        #pragma unroll
        for (int k = 0; k < 32; ++k) {
            float4 a4 = *(const float4*)(&St[k][4 * ty]);
            float4 b4 = *(const float4*)(&Wt[k][4 * tx]);
            float av[4] = {a4.x, a4.y, a4.z, a4.w};
            float bv[4] = {b4.x, b4.y, b4.z, b4.w};
            #pragma unroll
            for (int ri = 0; ri < 4; ++ri)
                #pragma unroll
                for (int oi = 0; oi < 4; ++oi)
                    acc[ri][oi] += av[ri] * bv[oi];
        }
    }

    float4 bs = *(const float4*)(bias + o0 + 4 * tx);
    float bsv[4] = {bs.x, bs.y, bs.z, bs.w};
    #pragma unroll
    for (int ri = 0; ri < 4; ++ri) {
        int row = row0 + 4 * ty + ri;
        float4 v;
        v.x = acc[ri][0] + bsv[0];
        v.y = acc[ri][1] + bsv[1];
        v.z = acc[ri][2] + bsv[2];
        v.w = acc[ri][3] + bsv[3];
        *(float4*)(up + (size_t)row * RDIM + o0 + 4 * tx) = v;
    }
}

// ---------------------------------------------------------------------------
// persistent cooperative scan - NO global barrier.
// Fine-grained producer-consumer gating:
//  - k-group g (rows 256g..256g+256) is produced by blocks 32g..32g+32.
//  - after a block's sc1 state stores are acked (vmcnt(0)) and all its waves
//    synced, tid0 atomicAdds group counter g = bid>>5.
//  - a wave may consume chunk c of slot t once cnt[c] >= 32*t (monotone).
//  - fast path: all 8 ready -> round-6 pipelined 8-chunk loop (proven);
//    else consume chunks as they become ready (stragglers overlap compute).
// Memory protocol unchanged (sc1 write-through once per address; cached reads
// first touched only after the gate => never stale; sc1-only polled lines).
// ---------------------------------------------------------------------------
__global__ __launch_bounds__(SCAN_THREADS, 2) void esn_scan(
    const float* __restrict__ W,      // (R, R)
    float* __restrict__ states,       // (T+1, B, R); slots 1..512 hold uproj
    unsigned* __restrict__ flags)     // group counters at flags[g*16], g=0..7
{
    __shared__ float Wl[ROWS_PER_BLK * RDIM];   // 64 KB

    const int tid  = threadIdx.x;
    const int bid  = blockIdx.x;
    const int r0   = bid * ROWS_PER_BLK;
    unsigned* gcnt = &flags[(bid >> 5) * 16];

    // ---- stage W slice (contiguous 64 KB) into LDS ----
    {
        const float4* src = (const float4*)(W + (size_t)r0 * RDIM);
        float4* dst = (float4*)Wl;
        #pragma unroll
        for (int i = 0; i < (ROWS_PER_BLK * RDIM) / 4 / SCAN_THREADS; ++i)
            dst[i * SCAN_THREADS + tid] = src[i * SCAN_THREADS + tid];
    }

    const int wave = tid >> 6;           // 0..7
    const int lane = tid & 63;           // 64-way k-split
    const int b0   = wave * 4;           // batches b0..b0+3
    const int kb   = lane * 4;           // k base within each 256-chunk

    const int bf = b0 + (lane & 3);      // finalize batch (lanes<32)
    const int rr = lane >> 2;            // finalize row   (lanes<32)
    const size_t fin_off = (size_t)bf * RDIM + r0 + rr;

    float so = 0.0f;
    if (lane < 32) so = states[fin_off];   // slot 0 = initial state

    float acc[8][4];                     // [row][batch]

    __syncthreads();   // Wl ready

    for (int t = 0; t < SEQ; ++t) {
        const float* prev = states + (size_t)t * (BATCH * RDIM);
        float* next = states + (size_t)(t + 1) * (BATCH * RDIM);
        const unsigned target = 32u * (unsigned)t;

        // uproj for this step (slot t+1, sc1 non-allocating read; consumed
        // after the reduction -> latency hidden under the dot)
        float up = 0.0f;
        if (lane < 32)
            up = __hip_atomic_load(&next[fin_off], __ATOMIC_RELAXED,
                                   __HIP_MEMORY_SCOPE_AGENT);

        #pragma unroll
        for (int r = 0; r < 8; ++r)
            #pragma unroll
            for (int bb = 0; bb < 4; ++bb) acc[r][bb] = 0.0f;

        // ---- gated recurrent dot ----
        unsigned ready = poll_ready(flags, lane, target);
        asm volatile("" ::: "memory");

        if (ready == 0xFFu) {
            // fast path: all producers done -> pipelined 8-chunk loop
            const float* sb = prev + kb;
            f4 s_cur[4], s_nxt[4];
            #pragma unroll
            for (int bb = 0; bb < 4; ++bb)
                s_cur[bb] = *(const f4*)(sb + (size_t)(b0 + bb) * RDIM);

            #pragma unroll 1
            for (int c = 0; c < 8; ++c) {
                if (c < 7) {
                    #pragma unroll
                    for (int bb = 0; bb < 4; ++bb)
                        s_nxt[bb] = *(const f4*)(sb + (size_t)(b0 + bb) * RDIM
                                                 + (c + 1) * 256);
                }
                const float* wl = &Wl[c * 256 + kb];
                #pragma unroll
                for (int r = 0; r < 8; ++r) {
                    f4 w4 = *(const f4*)(wl + r * RDIM);
                    #pragma unroll
                    for (int bb = 0; bb < 4; ++bb)
                        acc[r][bb] += w4[0] * s_cur[bb][0] + w4[1] * s_cur[bb][1]
                                    + w4[2] * s_cur[bb][2] + w4[3] * s_cur[bb][3];
                }
                #pragma unroll
                for (int bb = 0; bb < 4; ++bb) s_cur[bb] = s_nxt[bb];
            }
        } else {
            // slow path: consume chunks as their producer group completes
            unsigned done = 0;
            int ndone = 0;
            while (ndone < 8) {
                unsigned avail = ready & ~done;
                if (!avail) {
                    __builtin_amdgcn_s_sleep(1);
                    ready = poll_ready(flags, lane, target);
                    continue;
                }
                int c = __builtin_ctz(avail);
                done |= 1u << c;
                ++ndone;
                asm volatile("" ::: "memory");
                f4 s4[4];
                #pragma unroll
                for (int bb = 0; bb < 4; ++bb)
                    s4[bb] = *(const f4*)(prev + (size_t)(b0 + bb) * RDIM
                                          + c * 256 + kb);
                const float* wl = &Wl[c * 256 + kb];
                #pragma unroll
                for (int r = 0; r < 8; ++r) {
                    f4 w4 = *(const f4*)(wl + r * RDIM);
                    #pragma unroll
                    for (int bb = 0; bb < 4; ++bb)
                        acc[r][bb] += w4[0] * s4[bb][0] + w4[1] * s4[bb][1]
                                    + w4[2] * s4[bb][2] + w4[3] * s4[bb][3];
                }
            }
        }

        // ---- reduce 32 accs over 64 lanes ----
        #pragma unroll
        for (int r = 0; r < 8; ++r)
            #pragma unroll
            for (int bb = 0; bb < 4; ++bb) {
                float v = acc[r][bb];
                v += __shfl_xor(v, 1, 64);
                v += __shfl_xor(v, 2, 64);
                acc[r][bb] = v;
            }
        const int q = lane & 3;
        float v8[8];
        #pragma unroll
        for (int r = 0; r < 8; ++r) {
            float a01 = (q & 1) ? acc[r][1] : acc[r][0];
            float a23 = (q & 1) ? acc[r][3] : acc[r][2];
            float v   = (q & 2) ? a23 : a01;
            v += __shfl_xor(v, 4, 64);
            v += __shfl_xor(v, 8, 64);
            v += __shfl_xor(v, 16, 64);
            v += __shfl_xor(v, 32, 64);
            v8[r] = v;
        }

        // ---- finalize: pre = dot + uproj; sc1 write-through store ----
        if (lane < 32) {
            float pre = v8[0];
            #pragma unroll
            for (int r = 1; r < 8; ++r) if (rr == r) pre = v8[r];
            pre += up;
            float sn = (1.0f - LEAK) * so + LEAK * tanhf(pre);
            so = sn;   // register carry
            __hip_atomic_store(&next[fin_off], sn,
                               __ATOMIC_RELAXED, __HIP_MEMORY_SCOPE_AGENT);
        }

        // wave's stores acked at coherent point; block arrival -> group count
        asm volatile("s_waitcnt vmcnt(0)" ::: "memory");
        __syncthreads();
        if (tid == 0) atomicAdd(gcnt, 1u);
    }
}

// ---------------------------------------------------------------------------
// readout: out[b][t][o] = sum_r states[t+1][b][r] * w_ro[o][r] + b_ro[o]
// ---------------------------------------------------------------------------
#define RO_THREADS 256
__global__ __launch_bounds__(RO_THREADS) void esn_readout(
    const float* __restrict__ states,   // (T+1, B, R); rows (t*32+b) start at slot 1
    const float* __restrict__ w_ro,     // (O, R)
    const float* __restrict__ b_ro,     // (O)
    float* __restrict__ out)            // (B, T, O)
{
    __shared__ float St[32][68];
    __shared__ float Wt[32][68];

    const int tid  = threadIdx.x;
    const int rb   = blockIdx.x >> 2;
    const int ob   = blockIdx.x & 3;
    const int row0 = rb * 64;
    const int o0   = ob * 64;
    const float* S = states + (size_t)BATCH * RDIM;   // skip slot 0

    const int lr = tid >> 3;
    const int lk = (tid & 7) * 4;
    const int tx = tid & 15;
    const int ty = tid >> 4;

    float acc[4][4] = {};

    for (int kt = 0; kt < RDIM; kt += 32) {
        float4 a0 = *(const float4*)(S + (size_t)(row0 + lr)      * RDIM + kt + lk);
        float4 a1 = *(const float4*)(S + (size_t)(row0 + 32 + lr) * RDIM + kt + lk);
        float4 w0 = *(const float4*)(w_ro + (size_t)(o0 + lr)      * RDIM + kt + lk);
        float4 w1 = *(const float4*)(w_ro + (size_t)(o0 + 32 + lr) * RDIM + kt + lk);
        __syncthreads();
        float av0[4] = {a0.x, a0.y, a0.z, a0.w};
        float av1[4] = {a1.x, a1.y, a1.z, a1.w};
        float wv0[4] = {w0.x, w0.y, w0.z, w0.w};
        float wv1[4] = {w1.x, w1.y, w1.z, w1.w};
        #pragma unroll
        for (int j = 0; j < 4; ++j) {
            St[lk + j][lr]      = av0[j];
            St[lk + j][32 + lr] = av1[j];
            Wt[lk + j][lr]      = wv0[j];
            Wt[lk + j][32 + lr] = wv1[j];
        }
        __syncthreads();
        #pragma unroll
        for (int k = 0; k < 32; ++k) {
            float4 a4 = *(const float4*)(&St[k][4 * ty]);
            float4 b4 = *(const float4*)(&Wt[k][4 * tx]);
            float av[4] = {a4.x, a4.y, a4.z, a4.w};
            float bv[4] = {b4.x, b4.y, b4.z, b4.w};
            #pragma unroll
            for (int ri = 0; ri < 4; ++ri)
                #pragma unroll
                for (int oi = 0; oi < 4; ++oi)
                    acc[ri][oi] += av[ri] * bv[oi];
        }
    }

    float4 br = *(const float4*)(b_ro + o0 + 4 * tx);
    float brv[4] = {br.x, br.y, br.z, br.w};
    #pragma unroll
    for (int ri = 0; ri < 4; ++ri) {
        int row = row0 + 4 * ty + ri;
        int tt  = row >> 5;
        int bbx = row & 31;
        float4 v;
        v.x = acc[ri][0] + brv[0];
        v.y = acc[ri][1] + brv[1];
        v.z = acc[ri][2] + brv[2];
        v.w = acc[ri][3] + brv[3];
        *(float4*)(out + ((size_t)bbx * SEQ + tt) * ODIM + o0 + 4 * tx) = v;
    }
}

// ---------------------------------------------------------------------------
extern "C" void kernel_launch(void* const* d_in, const int* in_sizes, int n_in,
                              void* d_out, int out_size, void* d_ws, size_t ws_size,
                              hipStream_t stream) {
    const float* u    = (const float*)d_in[0];
    const float* s0   = (const float*)d_in[1];
    const float* Win  = (const float*)d_in[2];
    const float* W    = (const float*)d_in[3];
    const float* bias = (const float*)d_in[4];
    const float* w_ro = (const float*)d_in[5];
    const float* b_ro = (const float*)d_in[6];
    float* out = (float*)d_out;

    const size_t states_elems = (size_t)(SEQ + 1) * BATCH * RDIM;
    const size_t states_bytes = states_elems * sizeof(float);
    const size_t need = states_bytes + 2048;
    if (ws_size < need) return;   // visible failure rather than OOB writes

    float* states = (float*)d_ws;
    unsigned* flags = (unsigned*)((char*)d_ws + states_bytes);

    // slot 0 = initial state; counters = 0
    esn_init<<<dim3(64), dim3(256), 0, stream>>>(s0, states, flags);

    // slots 1..512 = u_proj[t] (+bias), aliasing states[t+1]
    esn_uproj<<<dim3((SEQ * BATCH) / 64, RDIM / 64), dim3(UP_THREADS), 0, stream>>>(
        u, Win, bias, states + (size_t)BATCH * RDIM);

    void* args[] = { (void*)&W, (void*)&states, (void*)&flags };
    hipLaunchCooperativeKernel((const void*)esn_scan,
                               dim3(SCAN_BLOCKS), dim3(SCAN_THREADS),
                               args, 0, stream);

    esn_readout<<<dim3((SEQ * BATCH / 64) * (ODIM / 64)), dim3(RO_THREADS), 0, stream>>>(
        states, w_ro, b_ro, out);
}

// Round 8
// 7875.489 us; speedup vs baseline: 1.8579x; 1.8579x over previous
//
#include <hip/hip_runtime.h>
#include <math.h>

#define BATCH 32
#define SEQ   512
#define IDIM  256
#define RDIM  2048
#define ODIM  256
#define LEAK  0.3f

#define SCAN_BLOCKS  256
#define SCAN_THREADS 512
#define ROWS_PER_BLK 8   // RDIM / SCAN_BLOCKS

typedef float f4 __attribute__((ext_vector_type(4)));

__device__ __forceinline__ unsigned ld_flag(const unsigned* p) {
    return __hip_atomic_load(p, __ATOMIC_RELAXED, __HIP_MEMORY_SCOPE_AGENT);
}
__device__ __forceinline__ void st_flag(unsigned* p, unsigned v) {
    __hip_atomic_store(p, v, __ATOMIC_RELAXED, __HIP_MEMORY_SCOPE_AGENT);
}

// ---------------------------------------------------------------------------
// init: copy initial state into states slot 0, zero flags region
// ---------------------------------------------------------------------------
__global__ void esn_init(const float* __restrict__ s0, float* __restrict__ states,
                         unsigned* __restrict__ flags) {
    int idx = blockIdx.x * blockDim.x + threadIdx.x;
    const int n4 = (BATCH * RDIM) / 4;
    if (idx < n4) {
        ((float4*)states)[idx] = ((const float4*)s0)[idx];
    }
    if (idx < 512) flags[idx] = 0u;
}

// ---------------------------------------------------------------------------
// u_proj GEMM: up[m][r] = sum_i u[b][t][i] * Win[r][i] + bias[r],  m = t*32+b
// Written into states slots 1..512 (up[t] aliases states[t+1]; consumed by the
// finalize lane via sc1 read before the same lane overwrites it).
// ---------------------------------------------------------------------------
#define UP_THREADS 256
__global__ __launch_bounds__(UP_THREADS) void esn_uproj(
    const float* __restrict__ u,      // (B, T, I)
    const float* __restrict__ Win,    // (R, I)
    const float* __restrict__ bias,   // (R)
    float* __restrict__ up)           // (T*B, R) == states + B*R
{
    __shared__ float St[32][68];
    __shared__ float Wt[32][68];

    const int tid  = threadIdx.x;
    const int row0 = blockIdx.x * 64;   // m-tile (m = t*32+b)
    const int o0   = blockIdx.y * 64;   // r-tile

    const int lr = tid >> 3;
    const int lk = (tid & 7) * 4;
    const int tx = tid & 15;
    const int ty = tid >> 4;

    const int m0 = row0 + lr;
    const int m1 = row0 + 32 + lr;
    const float* u0 = u + ((size_t)(m0 & 31) * SEQ + (m0 >> 5)) * IDIM;
    const float* u1 = u + ((size_t)(m1 & 31) * SEQ + (m1 >> 5)) * IDIM;

    float acc[4][4] = {};

    for (int kt = 0; kt < IDIM; kt += 32) {
        float4 a0 = *(const float4*)(u0 + kt + lk);
        float4 a1 = *(const float4*)(u1 + kt + lk);
        float4 w0 = *(const float4*)(Win + (size_t)(o0 + lr)      * IDIM + kt + lk);
        float4 w1 = *(const float4*)(Win + (size_t)(o0 + 32 + lr) * IDIM + kt + lk);
        __syncthreads();
        float av0[4] = {a0.x, a0.y, a0.z, a0.w};
        float av1[4] = {a1.x, a1.y, a1.z, a1.w};
        float wv0[4] = {w0.x, w0.y, w0.z, w0.w};
        float wv1[4] = {w1.x, w1.y, w1.z, w1.w};
        #pragma unroll
        for (int j = 0; j < 4; ++j) {
            St[lk + j][lr]      = av0[j];
            St[lk + j][32 + lr] = av1[j];
            Wt[lk + j][lr]      = wv0[j];
            Wt[lk + j][32 + lr] = wv1[j];
        }
        __syncthreads();
        #pragma unroll
        for (int k = 0; k < 32; ++k) {
            float4 a4 = *(const float4*)(&St[k][4 * ty]);
            float4 b4 = *(const float4*)(&Wt[k][4 * tx]);
            float av[4] = {a4.x, a4.y, a4.z, a4.w};
            float bv[4] = {b4.x, b4.y, b4.z, b4.w};
            #pragma unroll
            for (int ri = 0; ri < 4; ++ri)
                #pragma unroll
                for (int oi = 0; oi < 4; ++oi)
                    acc[ri][oi] += av[ri] * bv[oi];
        }
    }

    float4 bs = *(const float4*)(bias + o0 + 4 * tx);
    float bsv[4] = {bs.x, bs.y, bs.z, bs.w};
    #pragma unroll
    for (int ri = 0; ri < 4; ++ri) {
        int row = row0 + 4 * ty + ri;
        float4 v;
        v.x = acc[ri][0] + bsv[0];
        v.y = acc[ri][1] + bsv[1];
        v.z = acc[ri][2] + bsv[2];
        v.w = acc[ri][3] + bsv[3];
        *(float4*)(up + (size_t)row * RDIM + o0 + 4 * tx) = v;
    }
}

// ---------------------------------------------------------------------------
// persistent cooperative scan - round-6 structure (best measured), with the
// register allocator pinned to exactly 2 waves/EU (= the 1 block/CU this
// grid runs; LDS caps there anyway) so the 256-VGPR budget is actually USED.
// Rounds 4-7 all spilled ~136 B/thread/step to scratch (WRITE_SIZE 9-14 GB)
// because launch_bounds' min-waves only sets the ceiling; the occupancy
// heuristic still targeted high waves/EU and spilled down to 60 VGPRs.
// Protocol (proven rounds 3-6):
//  - state slot t+1 written exactly once via sc1 (write-through -> coherent
//    MALL); read with normal cached loads only after barrier t+1 => a line
//    can enter an XCD L2 only post-barrier, never stale. No cache maintenance.
//  - uproj read via sc1 by the same lane that overwrites it.
//  - flags are the only polled lines.
// ---------------------------------------------------------------------------
__global__ __launch_bounds__(SCAN_THREADS)
__attribute__((amdgpu_waves_per_eu(2, 2)))
void esn_scan(
    const float* __restrict__ W,      // (R, R)
    float* __restrict__ states,       // (T+1, B, R); slots 1..512 hold uproj
    unsigned* __restrict__ flags)     // [0..255] per-block step; [320] = go
{
    __shared__ float Wl[ROWS_PER_BLK * RDIM];   // 64 KB

    const int tid  = threadIdx.x;
    const int bid  = blockIdx.x;
    const int r0   = bid * ROWS_PER_BLK;
    unsigned* go   = flags + 320;

    // ---- stage W slice (contiguous 64 KB) into LDS ----
    {
        const float4* src = (const float4*)(W + (size_t)r0 * RDIM);
        float4* dst = (float4*)Wl;
        #pragma unroll
        for (int i = 0; i < (ROWS_PER_BLK * RDIM) / 4 / SCAN_THREADS; ++i)
            dst[i * SCAN_THREADS + tid] = src[i * SCAN_THREADS + tid];
    }

    const int wave = tid >> 6;           // 0..7
    const int lane = tid & 63;           // 64-way k-split
    const int b0   = wave * 4;           // batches b0..b0+3
    const int kb   = lane * 4;           // k base within each 256-chunk

    const int bf = b0 + (lane & 3);      // finalize batch (lanes<32)
    const int rr = lane >> 2;            // finalize row   (lanes<32)
    const size_t fin_off = (size_t)bf * RDIM + r0 + rr;

    // carry the finalize element's state in a register (slot 0 = s0)
    float so = 0.0f;
    if (lane < 32) so = states[fin_off];

    float acc[8][4];                     // [row][batch]

    __syncthreads();   // Wl ready

    for (int t = 0; t < SEQ; ++t) {
        const float* prev = states + (size_t)t * (BATCH * RDIM);
        float* next = states + (size_t)(t + 1) * (BATCH * RDIM);

        // uproj for this step lives in slot t+1; sc1 (non-allocating) read,
        // consumed after the reduction -> latency hidden by the dot loop
        float up = 0.0f;
        if (lane < 32)
            up = __hip_atomic_load(&next[fin_off], __ATOMIC_RELAXED,
                                   __HIP_MEMORY_SCOPE_AGENT);

        #pragma unroll
        for (int r = 0; r < 8; ++r)
            #pragma unroll
            for (int bb = 0; bb < 4; ++bb) acc[r][bb] = 0.0f;

        // ---- recurrent dot: 8 chunks of 256 k, 4-batch regs + prefetch ----
        {
            const float* sb = prev + kb;
            f4 s_cur[4], s_nxt[4];
            #pragma unroll
            for (int bb = 0; bb < 4; ++bb)
                s_cur[bb] = *(const f4*)(sb + (size_t)(b0 + bb) * RDIM);

            #pragma unroll 1
            for (int c = 0; c < 8; ++c) {
                if (c < 7) {
                    #pragma unroll
                    for (int bb = 0; bb < 4; ++bb)
                        s_nxt[bb] = *(const f4*)(sb + (size_t)(b0 + bb) * RDIM
                                                 + (c + 1) * 256);
                }
                const float* wl = &Wl[c * 256 + kb];
                #pragma unroll
                for (int r = 0; r < 8; ++r) {
                    f4 w4 = *(const f4*)(wl + r * RDIM);
                    #pragma unroll
                    for (int bb = 0; bb < 4; ++bb)
                        acc[r][bb] += w4[0] * s_cur[bb][0] + w4[1] * s_cur[bb][1]
                                    + w4[2] * s_cur[bb][2] + w4[3] * s_cur[bb][3];
                }
                #pragma unroll
                for (int bb = 0; bb < 4; ++bb) s_cur[bb] = s_nxt[bb];
            }
        }

        // ---- reduce 32 accs over 64 lanes ----
        #pragma unroll
        for (int r = 0; r < 8; ++r)
            #pragma unroll
            for (int bb = 0; bb < 4; ++bb) {
                float v = acc[r][bb];
                v += __shfl_xor(v, 1, 64);
                v += __shfl_xor(v, 2, 64);
                acc[r][bb] = v;
            }
        const int q = lane & 3;
        float v8[8];
        #pragma unroll
        for (int r = 0; r < 8; ++r) {
            float a01 = (q & 1) ? acc[r][1] : acc[r][0];
            float a23 = (q & 1) ? acc[r][3] : acc[r][2];
            float v   = (q & 2) ? a23 : a01;
            v += __shfl_xor(v, 4, 64);
            v += __shfl_xor(v, 8, 64);
            v += __shfl_xor(v, 16, 64);
            v += __shfl_xor(v, 32, 64);
            v8[r] = v;
        }

        // ---- finalize: pre = dot + uproj; sc1 write-through store ----
        if (lane < 32) {
            float pre = v8[0];
            #pragma unroll
            for (int r = 1; r < 8; ++r) if (rr == r) pre = v8[r];
            pre += up;
            float sn = (1.0f - LEAK) * so + LEAK * tanhf(pre);
            so = sn;   // register carry for step t+1
            __hip_atomic_store(&next[fin_off], sn,
                               __ATOMIC_RELAXED, __HIP_MEMORY_SCOPE_AGENT);
        }

        // own stores acked at coherent point, then block-wide flag
        asm volatile("s_waitcnt vmcnt(0)" ::: "memory");
        __syncthreads();
        if (tid == 0) st_flag(&flags[bid], (unsigned)(t + 1));
        asm volatile("" ::: "memory");

        // ---- barrier: block0/wave0 aggregates flags -> go; others poll go
        const unsigned tp = (unsigned)(t + 1);
        if (bid == 0) {
            if (tid < 64) {
                for (;;) {
                    unsigned f0 = ld_flag(&flags[tid]);
                    unsigned f1 = ld_flag(&flags[64 + tid]);
                    unsigned f2 = ld_flag(&flags[128 + tid]);
                    unsigned f3 = ld_flag(&flags[192 + tid]);
                    bool ok = (f0 >= tp) & (f1 >= tp) & (f2 >= tp) & (f3 >= tp);
                    if (__all(ok)) break;
                    __builtin_amdgcn_s_sleep(2);
                }
                asm volatile("" ::: "memory");
                if (tid == 0) st_flag(go, tp);
            }
        } else {
            if (tid == 0) {
                while (ld_flag(go) < tp) __builtin_amdgcn_s_sleep(2);
            }
        }
        __syncthreads();
    }
}

// ---------------------------------------------------------------------------
// readout: out[b][t][o] = sum_r states[t+1][b][r] * w_ro[o][r] + b_ro[o]
// ---------------------------------------------------------------------------
#define RO_THREADS 256
__global__ __launch_bounds__(RO_THREADS) void esn_readout(
    const float* __restrict__ states,   // (T+1, B, R); rows (t*32+b) start at slot 1
    const float* __restrict__ w_ro,     // (O, R)
    const float* __restrict__ b_ro,     // (O)
    float* __restrict__ out)            // (B, T, O)
{
    __shared__ float St[32][68];
    __shared__ float Wt[32][68];

    const int tid  = threadIdx.x;
    const int rb   = blockIdx.x >> 2;
    const int ob   = blockIdx.x & 3;
    const int row0 = rb * 64;
    const int o0   = ob * 64;
    const float* S = states + (size_t)BATCH * RDIM;   // skip slot 0

    const int lr = tid >> 3;
    const int lk = (tid & 7) * 4;
    const int tx = tid & 15;
    const int ty = tid >> 4;

    float acc[4][4] = {};

    for (int kt = 0; kt < RDIM; kt += 32) {
        float4 a0 = *(const float4*)(S + (size_t)(row0 + lr)      * RDIM + kt + lk);
        float4 a1 = *(const float4*)(S + (size_t)(row0 + 32 + lr) * RDIM + kt + lk);
        float4 w0 = *(const float4*)(w_ro + (size_t)(o0 + lr)      * RDIM + kt + lk);
        float4 w1 = *(const float4*)(w_ro + (size_t)(o0 + 32 + lr) * RDIM + kt + lk);
        __syncthreads();
        float av0[4] = {a0.x, a0.y, a0.z, a0.w};
        float av1[4] = {a1.x, a1.y, a1.z, a1.w};
        float wv0[4] = {w0.x, w0.y, w0.z, w0.w};
        float wv1[4] = {w1.x, w1.y, w1.z, w1.w};
        #pragma unroll
        for (int j = 0; j < 4; ++j) {
            St[lk + j][lr]      = av0[j];
            St[lk + j][32 + lr] = av1[j];
            Wt[lk + j][lr]      = wv0[j];
            Wt[lk + j][32 + lr] = wv1[j];
        }
        __syncthreads();
        #pragma unroll
        for (int k = 0; k < 32; ++k) {
            float4 a4 = *(const float4*)(&St[k][4 * ty]);
            float4 b4 = *(const float4*)(&Wt[k][4 * tx]);
            float av[4] = {a4.x, a4.y, a4.z, a4.w};
            float bv[4] = {b4.x, b4.y, b4.z, b4.w};
            #pragma unroll
            for (int ri = 0; ri < 4; ++ri)
                #pragma unroll
                for (int oi = 0; oi < 4; ++oi)
                    acc[ri][oi] += av[ri] * bv[oi];
        }
    }

    float4 br = *(const float4*)(b_ro + o0 + 4 * tx);
    float brv[4] = {br.x, br.y, br.z, br.w};
    #pragma unroll
    for (int ri = 0; ri < 4; ++ri) {
        int row = row0 + 4 * ty + ri;
        int tt  = row >> 5;
        int bbx = row & 31;
        float4 v;
        v.x = acc[ri][0] + brv[0];
        v.y = acc[ri][1] + brv[1];
        v.z = acc[ri][2] + brv[2];
        v.w = acc[ri][3] + brv[3];
        *(float4*)(out + ((size_t)bbx * SEQ + tt) * ODIM + o0 + 4 * tx) = v;
    }
}

// ---------------------------------------------------------------------------
extern "C" void kernel_launch(void* const* d_in, const int* in_sizes, int n_in,
                              void* d_out, int out_size, void* d_ws, size_t ws_size,
                              hipStream_t stream) {
    const float* u    = (const float*)d_in[0];
    const float* s0   = (const float*)d_in[1];
    const float* Win  = (const float*)d_in[2];
    const float* W    = (const float*)d_in[3];
    const float* bias = (const float*)d_in[4];
    const float* w_ro = (const float*)d_in[5];
    const float* b_ro = (const float*)d_in[6];
    float* out = (float*)d_out;

    const size_t states_elems = (size_t)(SEQ + 1) * BATCH * RDIM;
    const size_t states_bytes = states_elems * sizeof(float);
    const size_t need = states_bytes + 2048;
    if (ws_size < need) return;   // visible failure rather than OOB writes

    float* states = (float*)d_ws;
    unsigned* flags = (unsigned*)((char*)d_ws + states_bytes);

    // slot 0 = initial state; flags = 0
    esn_init<<<dim3(64), dim3(256), 0, stream>>>(s0, states, flags);

    // slots 1..512 = u_proj[t] (+bias), aliasing states[t+1]
    esn_uproj<<<dim3((SEQ * BATCH) / 64, RDIM / 64), dim3(UP_THREADS), 0, stream>>>(
        u, Win, bias, states + (size_t)BATCH * RDIM);

    void* args[] = { (void*)&W, (void*)&states, (void*)&flags };
    hipLaunchCooperativeKernel((const void*)esn_scan,
                               dim3(SCAN_BLOCKS), dim3(SCAN_THREADS),
                               args, 0, stream);

    esn_readout<<<dim3((SEQ * BATCH / 64) * (ODIM / 64)), dim3(RO_THREADS), 0, stream>>>(
        states, w_ro, b_ro, out);
}

// Round 9
// 5010.324 us; speedup vs baseline: 2.9203x; 1.5719x over previous
//
#include <hip/hip_runtime.h>
#include <math.h>

#define BATCH 32
#define SEQ   512
#define IDIM  256
#define RDIM  2048
#define ODIM  256
#define LEAK  0.3f

#define SCAN_BLOCKS  256
#define SCAN_THREADS 512
#define ROWS_PER_BLK 8   // RDIM / SCAN_BLOCKS

typedef float f4 __attribute__((ext_vector_type(4)));

__device__ __forceinline__ unsigned ld_flag(const unsigned* p) {
    return __hip_atomic_load(p, __ATOMIC_RELAXED, __HIP_MEMORY_SCOPE_AGENT);
}
__device__ __forceinline__ void st_flag(unsigned* p, unsigned v) {
    __hip_atomic_store(p, v, __ATOMIC_RELAXED, __HIP_MEMORY_SCOPE_AGENT);
}

// ---------------------------------------------------------------------------
// init: copy initial state into states slot 0, zero flags region
// ---------------------------------------------------------------------------
__global__ void esn_init(const float* __restrict__ s0, float* __restrict__ states,
                         unsigned* __restrict__ flags) {
    int idx = blockIdx.x * blockDim.x + threadIdx.x;
    const int n4 = (BATCH * RDIM) / 4;
    if (idx < n4) {
        ((float4*)states)[idx] = ((const float4*)s0)[idx];
    }
    if (idx < 512) flags[idx] = 0u;
}

// ---------------------------------------------------------------------------
// u_proj GEMM: up[m][r] = sum_i u[b][t][i] * Win[r][i] + bias[r],  m = t*32+b
// Written into states slots 1..512 (up[t] aliases states[t+1]; consumed by the
// finalize lane via sc1 read before the same lane overwrites it).
// ---------------------------------------------------------------------------
#define UP_THREADS 256
__global__ __launch_bounds__(UP_THREADS) void esn_uproj(
    const float* __restrict__ u,      // (B, T, I)
    const float* __restrict__ Win,    // (R, I)
    const float* __restrict__ bias,   // (R)
    float* __restrict__ up)           // (T*B, R) == states + B*R
{
    __shared__ float St[32][68];
    __shared__ float Wt[32][68];

    const int tid  = threadIdx.x;
    const int row0 = blockIdx.x * 64;   // m-tile (m = t*32+b)
    const int o0   = blockIdx.y * 64;   // r-tile

    const int lr = tid >> 3;
    const int lk = (tid & 7) * 4;
    const int tx = tid & 15;
    const int ty = tid >> 4;

    const int m0 = row0 + lr;
    const int m1 = row0 + 32 + lr;
    const float* u0 = u + ((size_t)(m0 & 31) * SEQ + (m0 >> 5)) * IDIM;
    const float* u1 = u + ((size_t)(m1 & 31) * SEQ + (m1 >> 5)) * IDIM;

    float acc[4][4] = {};

    for (int kt = 0; kt < IDIM; kt += 32) {
        float4 a0 = *(const float4*)(u0 + kt + lk);
        float4 a1 = *(const float4*)(u1 + kt + lk);
        float4 w0 = *(const float4*)(Win + (size_t)(o0 + lr)      * IDIM + kt + lk);
        float4 w1 = *(const float4*)(Win + (size_t)(o0 + 32 + lr) * IDIM + kt + lk);
        __syncthreads();
        float av0[4] = {a0.x, a0.y, a0.z, a0.w};
        float av1[4] = {a1.x, a1.y, a1.z, a1.w};
        float wv0[4] = {w0.x, w0.y, w0.z, w0.w};
        float wv1[4] = {w1.x, w1.y, w1.z, w1.w};
        #pragma unroll
        for (int j = 0; j < 4; ++j) {
            St[lk + j][lr]      = av0[j];
            St[lk + j][32 + lr] = av1[j];
            Wt[lk + j][lr]      = wv0[j];
            Wt[lk + j][32 + lr] = wv1[j];
        }
        __syncthreads();
        #pragma unroll
        for (int k = 0; k < 32; ++k) {
            float4 a4 = *(const float4*)(&St[k][4 * ty]);
            float4 b4 = *(const float4*)(&Wt[k][4 * tx]);
            float av[4] = {a4.x, a4.y, a4.z, a4.w};
            float bv[4] = {b4.x, b4.y, b4.z, b4.w};
            #pragma unroll
            for (int ri = 0; ri < 4; ++ri)
                #pragma unroll
                for (int oi = 0; oi < 4; ++oi)
                    acc[ri][oi] += av[ri] * bv[oi];
        }
    }

    float4 bs = *(const float4*)(bias + o0 + 4 * tx);
    float bsv[4] = {bs.x, bs.y, bs.z, bs.w};
    #pragma unroll
    for (int ri = 0; ri < 4; ++ri) {
        int row = row0 + 4 * ty + ri;
        float4 v;
        v.x = acc[ri][0] + bsv[0];
        v.y = acc[ri][1] + bsv[1];
        v.z = acc[ri][2] + bsv[2];
        v.w = acc[ri][3] + bsv[3];
        *(float4*)(up + (size_t)row * RDIM + o0 + 4 * tx) = v;
    }
}

// ===========================================================================
// Macro-expanded register file for the scan kernel. NO local arrays anywhere:
// rounds 2-8's accumulator array was never SROA'd (lived in scratch, or LDS
// in round 8 with 2e9 bank conflicts). Named variables force plain VGPRs.
// ===========================================================================
#define DECL_A(r)  float A##r##0 = 0.0f, A##r##1 = 0.0f, A##r##2 = 0.0f, A##r##3 = 0.0f;
#define ZERO_A(r)  A##r##0 = 0.0f; A##r##1 = 0.0f; A##r##2 = 0.0f; A##r##3 = 0.0f;
#define DOT_ROW(r) { f4 w = *(const f4*)(wl + (r) * RDIM); \
    A##r##0 += w[0]*SC0[0] + w[1]*SC0[1] + w[2]*SC0[2] + w[3]*SC0[3]; \
    A##r##1 += w[0]*SC1[0] + w[1]*SC1[1] + w[2]*SC1[2] + w[3]*SC1[3]; \
    A##r##2 += w[0]*SC2[0] + w[1]*SC2[1] + w[2]*SC2[2] + w[3]*SC2[3]; \
    A##r##3 += w[0]*SC3[0] + w[1]*SC3[1] + w[2]*SC3[2] + w[3]*SC3[3]; }
#define RED12(x)   { x += __shfl_xor(x, 1, 64); x += __shfl_xor(x, 2, 64); }
#define RED_A(r)   RED12(A##r##0) RED12(A##r##1) RED12(A##r##2) RED12(A##r##3)
#define COMPACT(r) float V##r; { \
    float x01 = (q & 1) ? A##r##1 : A##r##0; \
    float x23 = (q & 1) ? A##r##3 : A##r##2; \
    float v   = (q & 2) ? x23 : x01; \
    v += __shfl_xor(v, 4, 64);  v += __shfl_xor(v, 8, 64); \
    v += __shfl_xor(v, 16, 64); v += __shfl_xor(v, 32, 64); \
    V##r = v; }

// ---------------------------------------------------------------------------
// persistent cooperative scan - round-6 structure (best barrier), arrays
// replaced by named scalars. Protocol (proven rounds 3-8):
//  - state slot t+1 written exactly once via sc1 (write-through -> coherent
//    MALL); read with normal cached loads only after barrier t+1 => a line
//    can enter an XCD L2 only post-barrier, never stale. No cache maintenance.
//  - uproj read via sc1 by the same lane that overwrites it.
//  - flags are the only polled lines.
// ---------------------------------------------------------------------------
__global__ __launch_bounds__(SCAN_THREADS) void esn_scan(
    const float* __restrict__ W,      // (R, R)
    float* __restrict__ states,       // (T+1, B, R); slots 1..512 hold uproj
    unsigned* __restrict__ flags)     // [0..255] per-block step; [320] = go
{
    __shared__ float Wl[ROWS_PER_BLK * RDIM];   // 64 KB

    const int tid  = threadIdx.x;
    const int bid  = blockIdx.x;
    const int r0   = bid * ROWS_PER_BLK;
    unsigned* go   = flags + 320;

    // ---- stage W slice (contiguous 64 KB) into LDS ----
    {
        const float4* src = (const float4*)(W + (size_t)r0 * RDIM);
        float4* dst = (float4*)Wl;
        #pragma unroll
        for (int i = 0; i < (ROWS_PER_BLK * RDIM) / 4 / SCAN_THREADS; ++i)
            dst[i * SCAN_THREADS + tid] = src[i * SCAN_THREADS + tid];
    }

    const int wave = tid >> 6;           // 0..7
    const int lane = tid & 63;           // 64-way k-split
    const int b0   = wave * 4;           // batches b0..b0+3
    const int kb   = lane * 4;           // k base within each 256-chunk
    const int q    = lane & 3;

    const int bf = b0 + q;               // finalize batch (lanes<32)
    const int rr = lane >> 2;            // finalize row   (lanes<32)
    const size_t fin_off = (size_t)bf * RDIM + r0 + rr;

    // carry the finalize element's state in a register (slot 0 = s0)
    float so = 0.0f;
    if (lane < 32) so = states[fin_off];

    DECL_A(0) DECL_A(1) DECL_A(2) DECL_A(3)
    DECL_A(4) DECL_A(5) DECL_A(6) DECL_A(7)

    __syncthreads();   // Wl ready

    for (int t = 0; t < SEQ; ++t) {
        const float* prev = states + (size_t)t * (BATCH * RDIM);
        float* next = states + (size_t)(t + 1) * (BATCH * RDIM);

        // uproj for this step lives in slot t+1; sc1 (non-allocating) read,
        // consumed after the reduction -> latency hidden by the dot loop
        float up = 0.0f;
        if (lane < 32)
            up = __hip_atomic_load(&next[fin_off], __ATOMIC_RELAXED,
                                   __HIP_MEMORY_SCOPE_AGENT);

        ZERO_A(0) ZERO_A(1) ZERO_A(2) ZERO_A(3)
        ZERO_A(4) ZERO_A(5) ZERO_A(6) ZERO_A(7)

        // ---- recurrent dot: 8 chunks of 256 k, named regs + prefetch ----
        {
            const float* sb = prev + kb;
            f4 SC0 = *(const f4*)(sb + (size_t)(b0 + 0) * RDIM);
            f4 SC1 = *(const f4*)(sb + (size_t)(b0 + 1) * RDIM);
            f4 SC2 = *(const f4*)(sb + (size_t)(b0 + 2) * RDIM);
            f4 SC3 = *(const f4*)(sb + (size_t)(b0 + 3) * RDIM);

            #pragma unroll 1
            for (int c = 0; c < 8; ++c) {
                f4 SN0 = SC0, SN1 = SC1, SN2 = SC2, SN3 = SC3;
                if (c < 7) {
                    SN0 = *(const f4*)(sb + (size_t)(b0 + 0) * RDIM + (c + 1) * 256);
                    SN1 = *(const f4*)(sb + (size_t)(b0 + 1) * RDIM + (c + 1) * 256);
                    SN2 = *(const f4*)(sb + (size_t)(b0 + 2) * RDIM + (c + 1) * 256);
                    SN3 = *(const f4*)(sb + (size_t)(b0 + 3) * RDIM + (c + 1) * 256);
                }
                const float* wl = &Wl[c * 256 + kb];
                DOT_ROW(0) DOT_ROW(1) DOT_ROW(2) DOT_ROW(3)
                DOT_ROW(4) DOT_ROW(5) DOT_ROW(6) DOT_ROW(7)
                SC0 = SN0; SC1 = SN1; SC2 = SN2; SC3 = SN3;
            }
        }

        // ---- reduce over 64 lanes: quad stages then 16-quad stages ----
        RED_A(0) RED_A(1) RED_A(2) RED_A(3)
        RED_A(4) RED_A(5) RED_A(6) RED_A(7)
        COMPACT(0) COMPACT(1) COMPACT(2) COMPACT(3)
        COMPACT(4) COMPACT(5) COMPACT(6) COMPACT(7)

        // ---- finalize: pre = dot + uproj; sc1 write-through store ----
        if (lane < 32) {
            float pre = V0;
            if (rr == 1) pre = V1;
            if (rr == 2) pre = V2;
            if (rr == 3) pre = V3;
            if (rr == 4) pre = V4;
            if (rr == 5) pre = V5;
            if (rr == 6) pre = V6;
            if (rr == 7) pre = V7;
            pre += up;
            float sn = (1.0f - LEAK) * so + LEAK * tanhf(pre);
            so = sn;   // register carry for step t+1
            __hip_atomic_store(&next[fin_off], sn,
                               __ATOMIC_RELAXED, __HIP_MEMORY_SCOPE_AGENT);
        }

        // own stores acked at coherent point, then block-wide flag
        asm volatile("s_waitcnt vmcnt(0)" ::: "memory");
        __syncthreads();
        if (tid == 0) st_flag(&flags[bid], (unsigned)(t + 1));
        asm volatile("" ::: "memory");

        // ---- barrier: block0/wave0 aggregates flags -> go; others poll go
        const unsigned tp = (unsigned)(t + 1);
        if (bid == 0) {
            if (tid < 64) {
                for (;;) {
                    unsigned f0 = ld_flag(&flags[tid]);
                    unsigned f1 = ld_flag(&flags[64 + tid]);
                    unsigned f2 = ld_flag(&flags[128 + tid]);
                    unsigned f3 = ld_flag(&flags[192 + tid]);
                    bool ok = (f0 >= tp) & (f1 >= tp) & (f2 >= tp) & (f3 >= tp);
                    if (__all(ok)) break;
                    __builtin_amdgcn_s_sleep(2);
                }
                asm volatile("" ::: "memory");
                if (tid == 0) st_flag(go, tp);
            }
        } else {
            if (tid == 0) {
                while (ld_flag(go) < tp) __builtin_amdgcn_s_sleep(2);
            }
        }
        __syncthreads();
    }
}

// ---------------------------------------------------------------------------
// readout: out[b][t][o] = sum_r states[t+1][b][r] * w_ro[o][r] + b_ro[o]
// ---------------------------------------------------------------------------
#define RO_THREADS 256
__global__ __launch_bounds__(RO_THREADS) void esn_readout(
    const float* __restrict__ states,   // (T+1, B, R); rows (t*32+b) start at slot 1
    const float* __restrict__ w_ro,     // (O, R)
    const float* __restrict__ b_ro,     // (O)
    float* __restrict__ out)            // (B, T, O)
{
    __shared__ float St[32][68];
    __shared__ float Wt[32][68];

    const int tid  = threadIdx.x;
    const int rb   = blockIdx.x >> 2;
    const int ob   = blockIdx.x & 3;
    const int row0 = rb * 64;
    const int o0   = ob * 64;
    const float* S = states + (size_t)BATCH * RDIM;   // skip slot 0

    const int lr = tid >> 3;
    const int lk = (tid & 7) * 4;
    const int tx = tid & 15;
    const int ty = tid >> 4;

    float acc[4][4] = {};

    for (int kt = 0; kt < RDIM; kt += 32) {
        float4 a0 = *(const float4*)(S + (size_t)(row0 + lr)      * RDIM + kt + lk);
        float4 a1 = *(const float4*)(S + (size_t)(row0 + 32 + lr) * RDIM + kt + lk);
        float4 w0 = *(const float4*)(w_ro + (size_t)(o0 + lr)      * RDIM + kt + lk);
        float4 w1 = *(const float4*)(w_ro + (size_t)(o0 + 32 + lr) * RDIM + kt + lk);
        __syncthreads();
        float av0[4] = {a0.x, a0.y, a0.z, a0.w};
        float av1[4] = {a1.x, a1.y, a1.z, a1.w};
        float wv0[4] = {w0.x, w0.y, w0.z, w0.w};
        float wv1[4] = {w1.x, w1.y, w1.z, w1.w};
        #pragma unroll
        for (int j = 0; j < 4; ++j) {
            St[lk + j][lr]      = av0[j];
            St[lk + j][32 + lr] = av1[j];
            Wt[lk + j][lr]      = wv0[j];
            Wt[lk + j][32 + lr] = wv1[j];
        }
        __syncthreads();
        #pragma unroll
        for (int k = 0; k < 32; ++k) {
            float4 a4 = *(const float4*)(&St[k][4 * ty]);
            float4 b4 = *(const float4*)(&Wt[k][4 * tx]);
            float av[4] = {a4.x, a4.y, a4.z, a4.w};
            float bv[4] = {b4.x, b4.y, b4.z, b4.w};
            #pragma unroll
            for (int ri = 0; ri < 4; ++ri)
                #pragma unroll
                for (int oi = 0; oi < 4; ++oi)
                    acc[ri][oi] += av[ri] * bv[oi];
        }
    }

    float4 br = *(const float4*)(b_ro + o0 + 4 * tx);
    float brv[4] = {br.x, br.y, br.z, br.w};
    #pragma unroll
    for (int ri = 0; ri < 4; ++ri) {
        int row = row0 + 4 * ty + ri;
        int tt  = row >> 5;
        int bbx = row & 31;
        float4 v;
        v.x = acc[ri][0] + brv[0];
        v.y = acc[ri][1] + brv[1];
        v.z = acc[ri][2] + brv[2];
        v.w = acc[ri][3] + brv[3];
        *(float4*)(out + ((size_t)bbx * SEQ + tt) * ODIM + o0 + 4 * tx) = v;
    }
}

// ---------------------------------------------------------------------------
extern "C" void kernel_launch(void* const* d_in, const int* in_sizes, int n_in,
                              void* d_out, int out_size, void* d_ws, size_t ws_size,
                              hipStream_t stream) {
    const float* u    = (const float*)d_in[0];
    const float* s0   = (const float*)d_in[1];
    const float* Win  = (const float*)d_in[2];
    const float* W    = (const float*)d_in[3];
    const float* bias = (const float*)d_in[4];
    const float* w_ro = (const float*)d_in[5];
    const float* b_ro = (const float*)d_in[6];
    float* out = (float*)d_out;

    const size_t states_elems = (size_t)(SEQ + 1) * BATCH * RDIM;
    const size_t states_bytes = states_elems * sizeof(float);
    const size_t need = states_bytes + 2048;
    if (ws_size < need) return;   // visible failure rather than OOB writes

    float* states = (float*)d_ws;
    unsigned* flags = (unsigned*)((char*)d_ws + states_bytes);

    // slot 0 = initial state; flags = 0
    esn_init<<<dim3(64), dim3(256), 0, stream>>>(s0, states, flags);

    // slots 1..512 = u_proj[t] (+bias), aliasing states[t+1]
    esn_uproj<<<dim3((SEQ * BATCH) / 64, RDIM / 64), dim3(UP_THREADS), 0, stream>>>(
        u, Win, bias, states + (size_t)BATCH * RDIM);

    void* args[] = { (void*)&W, (void*)&states, (void*)&flags };
    hipLaunchCooperativeKernel((const void*)esn_scan,
                               dim3(SCAN_BLOCKS), dim3(SCAN_THREADS),
                               args, 0, stream);

    esn_readout<<<dim3((SEQ * BATCH / 64) * (ODIM / 64)), dim3(RO_THREADS), 0, stream>>>(
        states, w_ro, b_ro, out);
}